// Round 1
// baseline (989.889 us; speedup 1.0000x reference)
//
#include <hip/hip_runtime.h>

#define HH 256
#define WW 256
#define HWSZ (HH*WW)
#define CH 32

__device__ __forceinline__ float lrelu_f(float x){ return x >= 0.f ? x : 0.2f*x; }

// 1x1 conv over concat(short, long): y[b,o,hw] = bias[o] + sum_c w[o][c]*s + w[o][32+c]*l
__global__ __launch_bounds__(256) void conv1x1_kernel(
    const float* __restrict__ s, const float* __restrict__ l,
    const float* __restrict__ w, const float* __restrict__ bias,
    float* __restrict__ y)
{
    int gid = blockIdx.x*256 + threadIdx.x;   // over 2*HWSZ
    int b = gid >> 16;
    int pix = gid & (HWSZ-1);
    const float* sp = s + (size_t)b*CH*HWSZ + pix;
    const float* lp = l + (size_t)b*CH*HWSZ + pix;
    float acc[CH];
    #pragma unroll
    for (int o=0;o<CH;++o) acc[o] = bias[o];
    for (int c=0;c<CH;++c) {
        float v = sp[(size_t)c*HWSZ];
        #pragma unroll
        for (int o=0;o<CH;++o) acc[o] += w[o*64+c]*v;
    }
    for (int c=0;c<CH;++c) {
        float v = lp[(size_t)c*HWSZ];
        #pragma unroll
        for (int o=0;o<CH;++o) acc[o] += w[o*64+32+c]*v;
    }
    float* yp = y + (size_t)b*CH*HWSZ + pix;
    #pragma unroll
    for (int o=0;o<CH;++o) yp[(size_t)o*HWSZ] = acc[o];
}

// 3x3 conv, pad=1, Cout=32, Cin = 32*NP (phase 0 from x0, phase 1 from x1). Optional lrelu.
template<int NP>
__global__ __launch_bounds__(256) void conv3x3_kernel(
    const float* __restrict__ x0, const float* __restrict__ x1,
    const float* __restrict__ w, const float* __restrict__ bias,
    float* __restrict__ y, int relu)
{
    int gid = blockIdx.x*256 + threadIdx.x;   // over 2*HWSZ
    int b = gid >> 16;
    int pix = gid & (HWSZ-1);
    int h = pix >> 8, cw = pix & 255;
    const int CIN = 32*NP;
    float acc[CH];
    #pragma unroll
    for (int o=0;o<CH;++o) acc[o] = bias[o];
    #pragma unroll
    for (int p=0;p<NP;++p) {
        const float* src = (p==0) ? x0 : x1;
        const float* xb = src + (size_t)b*CH*HWSZ;
        for (int c=0;c<CH;++c) {
            const float* xp = xb + (size_t)c*HWSZ;
            float v[9];
            #pragma unroll
            for (int t=0;t<9;++t) {
                int hh = h + t/3 - 1;
                int wx = cw + t%3 - 1;
                v[t] = (hh>=0 && hh<HH && wx>=0 && wx<WW) ? xp[hh*WW+wx] : 0.f;
            }
            const float* wp = w + (size_t)(p*32 + c)*9;   // + o*CIN*9 + t
            #pragma unroll
            for (int o=0;o<CH;++o) {
                #pragma unroll
                for (int t=0;t<9;++t)
                    acc[o] += wp[(size_t)o*CIN*9 + t] * v[t];
            }
        }
    }
    float* yp = y + (size_t)b*CH*HWSZ + pix;
    #pragma unroll
    for (int o=0;o<CH;++o)
        yp[(size_t)o*HWSZ] = relu ? lrelu_f(acc[o]) : acc[o];
}

// bilinear x2 upsample (align_corners=False) of [2,32,128,128] -> [2,32,256,256], times 2.0
__global__ __launch_bounds__(256) void up2_kernel(
    const float* __restrict__ x, float* __restrict__ y)
{
    int gid = blockIdx.x*256 + threadIdx.x;   // over 2*32*256*256
    int ow = gid & 255;
    int oh = (gid >> 8) & 255;
    int bc = gid >> 16;                        // 0..63
    const int Hin = 128, Win = 128;
    float cy = (oh + 0.5f)*0.5f - 0.5f;
    float cx = (ow + 0.5f)*0.5f - 0.5f;
    cy = fminf(fmaxf(cy, 0.f), (float)(Hin-1));
    cx = fminf(fmaxf(cx, 0.f), (float)(Win-1));
    int y0 = (int)floorf(cy);
    int x0 = (int)floorf(cx);
    int y1 = min(y0+1, Hin-1);
    int x1 = min(x0+1, Win-1);
    float ty = cy - (float)y0, tx = cx - (float)x0;
    const float* xp = x + (size_t)bc*Hin*Win;
    float v00 = xp[y0*Win+x0], v01 = xp[y0*Win+x1];
    float v10 = xp[y1*Win+x0], v11 = xp[y1*Win+x1];
    float v = v00*(1.f-ty)*(1.f-tx) + v01*(1.f-ty)*tx + v10*ty*(1.f-tx) + v11*ty*tx;
    y[gid] = 2.0f*v;
}

// 3x3 conv 32 -> 216 (no act) for one batch, rows [r0, r0+rows). blockIdx.y picks 24 out-chans.
// om layout: [216][rows][W]
__global__ __launch_bounds__(256) void dcn_off_kernel(
    const float* __restrict__ x,    // off batch base [32,H,W]
    const float* __restrict__ w,    // [216,32,9]
    const float* __restrict__ bias,
    float* __restrict__ om,
    int r0, int rows)
{
    int rr = blockIdx.x;
    int cw = threadIdx.x;
    int h = r0 + rr;
    int oc0 = blockIdx.y*24;
    float acc[24];
    #pragma unroll
    for (int j=0;j<24;++j) acc[j] = bias[oc0+j];
    for (int c=0;c<32;++c) {
        const float* xp = x + (size_t)c*HWSZ;
        float v[9];
        #pragma unroll
        for (int t=0;t<9;++t) {
            int hh = h + t/3 - 1;
            int wx = cw + t%3 - 1;
            v[t] = (hh>=0 && hh<HH && wx>=0 && wx<WW) ? xp[hh*WW+wx] : 0.f;
        }
        const float* wp = w + (size_t)c*9;   // + (oc0+j)*288 + t
        #pragma unroll
        for (int j=0;j<24;++j) {
            #pragma unroll
            for (int t=0;t<9;++t)
                acc[j] += wp[(size_t)(oc0+j)*288 + t] * v[t];
        }
    }
    #pragma unroll
    for (int j=0;j<24;++j)
        om[(size_t)(oc0+j)*rows*WW + (size_t)rr*WW + cw] = acc[j];
}

// DCNv2 sampling + 32-out einsum + bias + lrelu. One row per block; one pixel per thread.
__global__ __launch_bounds__(256) void dcn_kernel(
    const float* __restrict__ x,    // long_fea batch base [32,H,W]
    const float* __restrict__ om,   // [216][rows][W]
    const float* __restrict__ w,    // [32,32,9]
    const float* __restrict__ bias,
    float* __restrict__ y,          // out batch base [32,H,W]
    int r0, int rows)
{
    int rr = blockIdx.x;
    int cw = threadIdx.x;
    int h = r0 + rr;
    size_t ppos = (size_t)rr*WW + cw;
    size_t cstride = (size_t)rows*WW;
    float acc[CH];
    #pragma unroll
    for (int o=0;o<CH;++o) acc[o] = bias[o];
    for (int g=0; g<8; ++g) {
        const float* xg = x + (size_t)g*4*HWSZ;
        #pragma unroll
        for (int k=0;k<9;++k) {
            int oc = g*9+k;
            float dy = om[(size_t)oc*cstride + ppos];
            float dx = om[(size_t)(72+oc)*cstride + ppos];
            float mm = om[(size_t)(144+oc)*cstride + ppos];
            mm = 1.f/(1.f + __expf(-mm) );
            float py = dy + (float)(h + k/3 - 1);
            float px = dx + (float)(cw + k%3 - 1);
            float y0f = floorf(py), x0f = floorf(px);
            int yi = (int)y0f, xi = (int)x0f;
            float ty = py - y0f, tx = px - x0f;
            float w00 = (1.f-ty)*(1.f-tx), w01 = (1.f-ty)*tx;
            float w10 = ty*(1.f-tx),       w11 = ty*tx;
            int yc0 = min(max(yi,0),HH-1),   yc1 = min(max(yi+1,0),HH-1);
            int xc0 = min(max(xi,0),WW-1),   xc1 = min(max(xi+1,0),WW-1);
            bool vy0 = (yi>=0)&&(yi<HH),     vy1 = (yi+1>=0)&&(yi+1<HH);
            bool vx0 = (xi>=0)&&(xi<WW),     vx1 = (xi+1>=0)&&(xi+1<WW);
            float f00 = (vy0&&vx0)? w00*mm : 0.f;
            float f01 = (vy0&&vx1)? w01*mm : 0.f;
            float f10 = (vy1&&vx0)? w10*mm : 0.f;
            float f11 = (vy1&&vx1)? w11*mm : 0.f;
            int i00 = yc0*WW+xc0, i01 = yc0*WW+xc1;
            int i10 = yc1*WW+xc0, i11 = yc1*WW+xc1;
            #pragma unroll
            for (int c=0;c<4;++c) {
                const float* xc = xg + (size_t)c*HWSZ;
                float val = xc[i00]*f00 + xc[i01]*f01 + xc[i10]*f10 + xc[i11]*f11;
                const float* wp = w + (size_t)(g*4+c)*9 + k;   // + o*288
                #pragma unroll
                for (int o=0;o<CH;++o)
                    acc[o] += wp[(size_t)o*288] * val;
            }
        }
    }
    float* yp = y + (size_t)h*WW + cw;
    #pragma unroll
    for (int o=0;o<CH;++o) yp[(size_t)o*HWSZ] = lrelu_f(acc[o]);
}

extern "C" void kernel_launch(void* const* d_in, const int* in_sizes, int n_in,
                              void* d_out, int out_size, void* d_ws, size_t ws_size,
                              hipStream_t stream)
{
    (void)in_sizes; (void)n_in; (void)out_size;
    const float* short_fea = (const float*)d_in[0];
    const float* long_fea  = (const float*)d_in[1];
    const float* prev      = (const float*)d_in[2];
    const float* conv1_w   = (const float*)d_in[3];
    const float* conv1_b   = (const float*)d_in[4];
    const float* oc1_w     = (const float*)d_in[5];
    const float* oc1_b     = (const float*)d_in[6];
    const float* oc2_w     = (const float*)d_in[7];
    const float* oc2_b     = (const float*)d_in[8];
    const float* oc3_w     = (const float*)d_in[9];
    const float* oc3_b     = (const float*)d_in[10];
    const float* dow       = (const float*)d_in[11];
    const float* dob       = (const float*)d_in[12];
    const float* dcw       = (const float*)d_in[13];
    const float* dcb       = (const float*)d_in[14];

    float* out = (float*)d_out;                       // [2,32,256,256]
    float* off_out = out + (size_t)2*CH*HWSZ;         // [2,32,256,256]

    float* bufB = (float*)d_ws;                       // 16 MB
    float* bufU = bufB + (size_t)2*CH*HWSZ;           // 16 MB
    float* om   = bufU + (size_t)2*CH*HWSZ;           // rest: om chunk [216][rows][W]
    size_t used = (size_t)2 * 2*CH*HWSZ * sizeof(float);
    size_t avail = (ws_size > used) ? (ws_size - used) : 0;
    size_t per_row = (size_t)216 * WW * sizeof(float);
    int rows_chunk = (int)(avail / per_row);
    if (rows_chunk < 1) rows_chunk = 1;
    if (rows_chunk > HH) rows_chunk = HH;

    const int PIX_BLOCKS = (2*HWSZ)/256;   // 512

    // conv1 (1x1, no act): (short,long) -> out region (temp)
    conv1x1_kernel<<<PIX_BLOCKS, 256, 0, stream>>>(short_fea, long_fea, conv1_w, conv1_b, out);
    // oc1 (3x3, lrelu): out -> bufB
    conv3x3_kernel<1><<<PIX_BLOCKS, 256, 0, stream>>>(out, nullptr, oc1_w, oc1_b, bufB, 1);
    // up2: prev -> bufU  (includes the *2.0)
    up2_kernel<<<(2*CH*HWSZ)/256, 256, 0, stream>>>(prev, bufU);
    // oc2 (3x3 on concat(bufB,bufU), lrelu): -> out region (temp)
    conv3x3_kernel<2><<<PIX_BLOCKS, 256, 0, stream>>>(bufB, bufU, oc2_w, oc2_b, out, 1);
    // oc3 (3x3, lrelu): out -> off_out  (this is output #2)
    conv3x3_kernel<1><<<PIX_BLOCKS, 256, 0, stream>>>(out, nullptr, oc3_w, oc3_b, off_out, 1);

    // DCN: per batch, per row-chunk: offset conv (32->216) then sampling+einsum
    for (int b=0;b<2;++b) {
        const float* offb = off_out + (size_t)b*CH*HWSZ;
        const float* lfb  = long_fea + (size_t)b*CH*HWSZ;
        float* outb = out + (size_t)b*CH*HWSZ;
        for (int r0=0;r0<HH;r0+=rows_chunk) {
            int rows = (HH - r0 < rows_chunk) ? (HH - r0) : rows_chunk;
            dim3 g1(rows, 9);
            dcn_off_kernel<<<g1, 256, 0, stream>>>(offb, dow, dob, om, r0, rows);
            dcn_kernel<<<rows, 256, 0, stream>>>(lfb, om, dcw, dcb, outb, r0, rows);
        }
    }
}